// Round 1
// 10295.428 us; speedup vs baseline: 1.1295x; 1.1295x over previous
//
#include <hip/hip_runtime.h>
#include <math.h>

#define BATCH 512
#define SEQ   200
#define DIN   64
#define HID   512
#define GW    2048   // 4*HID
#define EPS   1e-5f
#define NREG  7      // G regions: ih0 | hh0 x2 | ih1 x2 | hh1 x2

typedef _Float16 half_t;
typedef half_t half8 __attribute__((ext_vector_type(8)));
typedef float  f32x4 __attribute__((ext_vector_type(4)));

#define WN0 (2048*64)     // W_ih0 elems
#define WN1 (2048*512)    // W_hh0 / W_ih1 / W_hh1 elems
#define WTOT (WN0 + 3*WN1)

__device__ __forceinline__ float sigf(float x){ return 1.0f/(1.0f+expf(-x)); }

// Reduce 4 values across a 256-thread block. red must be float[16] shared.
__device__ __forceinline__ void block_reduce4(float&a,float&b,float&c,float&d,float* red){
  #pragma unroll
  for(int o=32;o;o>>=1){
    a+=__shfl_down(a,o); b+=__shfl_down(b,o);
    c+=__shfl_down(c,o); d+=__shfl_down(d,o);
  }
  const int lane = threadIdx.x & 63, wid = threadIdx.x>>6;
  if(lane==0){ red[wid*4+0]=a; red[wid*4+1]=b; red[wid*4+2]=c; red[wid*4+3]=d; }
  __syncthreads();
  a = red[0]+red[4]+red[8]+red[12];
  b = red[1]+red[5]+red[9]+red[13];
  c = red[2]+red[6]+red[10]+red[14];
  d = red[3]+red[7]+red[11]+red[15];
  __syncthreads();
}

// Per-batch-row stats for ln1 (joint LayerNorm over (S,D) = 12800 elems)
__global__ __launch_bounds__(256) void ln1_stats(const float* __restrict__ x,
                                                 float* __restrict__ mu,
                                                 float* __restrict__ rs){
  const int b = blockIdx.x;
  const float* xb = x + (size_t)b*SEQ*DIN;
  float s=0, ss=0, d=0, e=0;
  for (int i=threadIdx.x; i<SEQ*DIN; i+=256){ float v=xb[i]; s+=v; ss+=v*v; }
  __shared__ float red[16];
  block_reduce4(s,ss,d,e,red);
  if (threadIdx.x==0){
    float m = s*(1.0f/(SEQ*DIN));
    mu[b] = m;
    rs[b] = rsqrtf(ss*(1.0f/(SEQ*DIN)) - m*m + EPS);
  }
}

// Split the 4 weight matrices (fp32, (N,K) row-major) into fp16 hi/lo, concat layout.
__global__ __launch_bounds__(256) void wsplit(
    const float* __restrict__ W0, const float* __restrict__ W1,
    const float* __restrict__ W2, const float* __restrict__ W3,
    half_t* __restrict__ Wh, half_t* __restrict__ Wl)
{
  int i = blockIdx.x*256 + threadIdx.x;
  if (i >= WTOT) return;
  const float* src; int off;
  if      (i < WN0)        { src=W0; off=i; }
  else if (i < WN0+WN1)    { src=W1; off=i-WN0; }
  else if (i < WN0+2*WN1)  { src=W2; off=i-WN0-WN1; }
  else                     { src=W3; off=i-WN0-2*WN1; }
  float v = src[off];
  half_t h = (half_t)v;
  Wh[i] = h;
  Wl[i] = (half_t)(v - (float)h);
}

// One tick: gate pre-activation GEMMs via split-fp16 MFMA (3-product), layer-1 skewed.
// Split-K x2 on the three K=512 GEMMs for occupancy (2 -> 3.5 waves/SIMD).
// grid.z = 7 regions:
//   z=0          : G_ih0 = ln1(x[:,t,:]) @ W_ih0^T   (K=64, A built in-register)
//   z=1,2        : G_hh0 = h0 @ W_hh0^T   k-halves 0/1
//   z=3,4        : G_ih1 = h0 @ W_ih1^T   k-halves 0/1
//   z=5,6        : G_hh1 = h1 @ W_hh1^T   k-halves 0/1
// Bias moved into tick_update (must only be added once under split-K).
// grid = (16 n-blks, 8 m-blks, 7), block = 256 (4 waves, 2x2), wave tile 32x64
__global__ __launch_bounds__(256) void tick_mm16(
    const float* __restrict__ x, const float* __restrict__ g1, const float* __restrict__ b1,
    const float* __restrict__ mu, const float* __restrict__ rsg,
    const half_t* __restrict__ h0h, const half_t* __restrict__ h0l,
    const half_t* __restrict__ h1h, const half_t* __restrict__ h1l,
    const half_t* __restrict__ Wh, const half_t* __restrict__ Wl,
    float* __restrict__ G, int t)
{
  const int z     = blockIdx.z;
  const int which = (z+1)>>1;            // 0,1,1,2,2,3,3
  const int khalf = z ? ((z-1)&1) : 0;   // -,0,1,0,1,0,1
  const int tid  = threadIdx.x;
  const int lane = tid & 63;
  const int w    = tid >> 6;
  const int lrow = lane & 15;          // row within a 16-tile (A: m, B: n, D: col)
  const int lk   = (lane >> 4) * 8;    // k offset within the 32-chunk

  const int wm0 = blockIdx.y*64 + (w>>1)*32;   // wave m origin (32 rows)
  const int wn0 = blockIdx.x*128 + (w&1)*64;   // wave n origin (64 cols)

  const half_t* Ah = h0h; const half_t* Al = h0l;
  const half_t* Bh = Wh + WN0; const half_t* Bl = Wl + WN0;
  int Kd = HID;
  if (which==0){ Bh=Wh; Bl=Wl; Kd=DIN; }
  else if (which==2){ Bh=Wh+WN0+WN1; Bl=Wl+WN0+WN1; }
  else if (which==3){ Ah=h1h; Al=h1l; Bh=Wh+WN0+2*WN1; Bl=Wl+WN0+2*WN1; }

  int kbeg, kend;
  if (which==0){ kbeg = 0; kend = DIN; }
  else         { kbeg = khalf*(HID/2); kend = kbeg + HID/2; }

  const int tq = (t < SEQ) ? t : (SEQ-1);   // t==200 layer0 result unused

  f32x4 acc[2][4];
  #pragma unroll
  for (int mi=0;mi<2;mi++)
    #pragma unroll
    for (int ni=0;ni<4;ni++)
      acc[mi][ni] = (f32x4){0.f,0.f,0.f,0.f};

  for (int k0 = kbeg; k0 < kend; k0 += 32) {
    half8 a_h[2], a_l[2], b_hv[4], b_lv[4];
    #pragma unroll
    for (int ni=0;ni<4;ni++){
      const size_t boff = (size_t)(wn0+ni*16+lrow)*Kd + k0 + lk;
      b_hv[ni] = *(const half8*)(Bh + boff);
      b_lv[ni] = *(const half8*)(Bl + boff);
    }
    #pragma unroll
    for (int mi=0;mi<2;mi++){
      if (which == 0) {
        const int b = wm0 + mi*16 + lrow;
        const float m_ = mu[b], r_ = rsg[b];
        const float* xp = x  + (size_t)b*(SEQ*DIN) + (size_t)tq*DIN + k0 + lk;
        const float* gp = g1 + (size_t)tq*DIN + k0 + lk;
        const float* bp = b1 + (size_t)tq*DIN + k0 + lk;
        #pragma unroll
        for (int j=0;j<8;j++){
          float v = (xp[j]-m_)*r_*gp[j] + bp[j];
          half_t hv = (half_t)v;
          a_h[mi][j] = hv;
          a_l[mi][j] = (half_t)(v - (float)hv);
        }
      } else {
        const size_t aoff = (size_t)(wm0+mi*16+lrow)*Kd + k0 + lk;
        a_h[mi] = *(const half8*)(Ah + aoff);
        a_l[mi] = *(const half8*)(Al + aoff);
      }
    }
    #pragma unroll
    for (int mi=0;mi<2;mi++)
      #pragma unroll
      for (int ni=0;ni<4;ni++){
        acc[mi][ni] = __builtin_amdgcn_mfma_f32_16x16x32_f16(a_h[mi], b_hv[ni], acc[mi][ni], 0,0,0);
        acc[mi][ni] = __builtin_amdgcn_mfma_f32_16x16x32_f16(a_l[mi], b_hv[ni], acc[mi][ni], 0,0,0);
        acc[mi][ni] = __builtin_amdgcn_mfma_f32_16x16x32_f16(a_h[mi], b_lv[ni], acc[mi][ni], 0,0,0);
      }
  }

  // C/D layout: col = lane&15, row = (lane>>4)*4 + r  (dtype-independent, m89-verified)
  // Nontemporal: G is streamed, consumed once by tick_update — keep L2 for weights.
  float* Gout = G + (size_t)z*BATCH*GW;
  #pragma unroll
  for (int mi=0;mi<2;mi++){
    const int mb = wm0 + mi*16 + (lane>>4)*4;
    #pragma unroll
    for (int ni=0;ni<4;ni++){
      const int n = wn0 + ni*16 + lrow;
      #pragma unroll
      for (int r=0;r<4;r++)
        __builtin_nontemporal_store(acc[mi][ni][r], &Gout[(size_t)(mb+r)*GW + n]);
    }
  }
}

// One block per (layer, batch-row): split-K sum + bias + gate LN + cell update + h LN.
__global__ __launch_bounds__(256) void tick_update(
    const float* __restrict__ G,
    const float* __restrict__ b_ih0, const float* __restrict__ b_hh0,
    const float* __restrict__ b_ih1, const float* __restrict__ b_hh1,
    const float* __restrict__ g_ih0, const float* __restrict__ be_ih0,
    const float* __restrict__ g_hh0, const float* __restrict__ be_hh0,
    const float* __restrict__ g_ho0, const float* __restrict__ be_ho0,
    const float* __restrict__ g_ih1, const float* __restrict__ be_ih1,
    const float* __restrict__ g_hh1, const float* __restrict__ be_hh1,
    const float* __restrict__ g_ho1, const float* __restrict__ be_ho1,
    float* __restrict__ h0, float* __restrict__ c0,
    float* __restrict__ h1, float* __restrict__ c1,
    half_t* __restrict__ h0h, half_t* __restrict__ h0l,
    half_t* __restrict__ h1h, half_t* __restrict__ h1l, int t)
{
  const int layer = blockIdx.x >> 9;
  const int b = blockIdx.x & 511;
  if (layer==0 && t>=SEQ) return;   // layer0 active ticks 0..199
  if (layer==1 && t==0)   return;   // layer1 active ticks 1..200 (processes step t-1)

  const float *GA0,*GA1,*GB0,*GB1,*bA,*bB,*gA,*beA,*gB,*beB,*gH,*bH;
  float *cs,*hs; half_t *hhx,*hlx;
  const size_t rb = (size_t)b*GW;
  if (layer==0){
    GA0 = G + rb;                        GA1 = nullptr;
    GB0 = G + (size_t)1*BATCH*GW + rb;   GB1 = G + (size_t)2*BATCH*GW + rb;
    bA=b_ih0; bB=b_hh0;
    gA=g_ih0; beA=be_ih0; gB=g_hh0; beB=be_hh0; gH=g_ho0; bH=be_ho0;
    cs = c0 + b*HID; hs = h0 + b*HID; hhx = h0h + b*HID; hlx = h0l + b*HID;
  } else {
    GA0 = G + (size_t)3*BATCH*GW + rb;   GA1 = G + (size_t)4*BATCH*GW + rb;
    GB0 = G + (size_t)5*BATCH*GW + rb;   GB1 = G + (size_t)6*BATCH*GW + rb;
    bA=b_ih1; bB=b_hh1;
    gA=g_ih1; beA=be_ih1; gB=g_hh1; beB=be_hh1; gH=g_ho1; bH=be_ho1;
    cs = c1 + b*HID; hs = h1 + b*HID; hhx = h1h + b*HID; hlx = h1l + b*HID;
  }

  const int tid = threadIdx.x;
  __shared__ float red[16];
  __shared__ __align__(16) float GS[2*GW];     // 16 KB: A-part then B-part
  __shared__ float su[HID];
  __shared__ float so[HID];

  // Pass 1 (float4): split-K sum + bias, stage into LDS, LN stats for both vectors
  float sa=0, ssa=0, sb=0, ssb=0;
  for (int i=tid*4; i<GW; i+=1024){
    f32x4 va = *(const f32x4*)(GA0+i);
    if (GA1) va += *(const f32x4*)(GA1+i);
    va += *(const f32x4*)(bA+i);
    *(f32x4*)(GS+i) = va;
    f32x4 vb = *(const f32x4*)(GB0+i);
    vb += *(const f32x4*)(GB1+i);
    vb += *(const f32x4*)(bB+i);
    *(f32x4*)(GS+GW+i) = vb;
    #pragma unroll
    for (int q=0;q<4;q++){
      sa += va[q]; ssa += va[q]*va[q];
      sb += vb[q]; ssb += vb[q]*vb[q];
    }
  }
  block_reduce4(sa,ssa,sb,ssb,red);   // internal __syncthreads covers GS visibility
  const float ma = sa*(1.0f/GW);
  const float ra = rsqrtf(ssa*(1.0f/GW) - ma*ma + EPS);
  const float mb = sb*(1.0f/GW);
  const float rb_ = rsqrtf(ssb*(1.0f/GW) - mb*mb + EPS);

  // Pass 2: gates (i,f,g,o split), cell update, tanh(c) stats
  float s_u=0, s_uu=0;
  for (int j=tid;j<HID;j+=256){
    float iv = ((GS[j      ]-ma)*ra*gA[j      ]+beA[j      ]) + ((GS[GW+j      ]-mb)*rb_*gB[j      ]+beB[j      ]);
    float fv = ((GS[j+  HID]-ma)*ra*gA[j+  HID]+beA[j+  HID]) + ((GS[GW+j+  HID]-mb)*rb_*gB[j+  HID]+beB[j+  HID]);
    float gv = ((GS[j+2*HID]-ma)*ra*gA[j+2*HID]+beA[j+2*HID]) + ((GS[GW+j+2*HID]-mb)*rb_*gB[j+2*HID]+beB[j+2*HID]);
    float ov = ((GS[j+3*HID]-ma)*ra*gA[j+3*HID]+beA[j+3*HID]) + ((GS[GW+j+3*HID]-mb)*rb_*gB[j+3*HID]+beB[j+3*HID]);
    float cn = sigf(fv)*cs[j] + sigf(iv)*tanhf(gv);
    cs[j] = cn;
    float u = tanhf(cn);
    su[j] = u; so[j] = sigf(ov);
    s_u += u; s_uu += u*u;
  }
  float d3=0,d4=0;
  block_reduce4(s_u,s_uu,d3,d4,red);
  const float mu_u = s_u*(1.0f/HID);
  const float ru   = rsqrtf(s_uu*(1.0f/HID) - mu_u*mu_u + EPS);

  // Pass 3: h = sigmoid(o) * LN(tanh(c)); emit fp32 + fp16 hi/lo split
  for (int j=tid;j<HID;j+=256){
    float v = so[j] * ((su[j]-mu_u)*ru*gH[j] + bH[j]);
    hs[j] = v;
    half_t hv = (half_t)v;
    hhx[j] = hv;
    hlx[j] = (half_t)(v - (float)hv);
  }
}

// Dense head: 512 -> 128 -> 64 -> 32 -> 1, one block per batch row
__global__ __launch_bounds__(256) void head_kernel(
    const float* __restrict__ h1,
    const float* __restrict__ Wd1, const float* __restrict__ bd1,
    const float* __restrict__ Wd2, const float* __restrict__ bd2,
    const float* __restrict__ Wd3, const float* __restrict__ bd3,
    const float* __restrict__ Wd4, const float* __restrict__ bd4,
    float* __restrict__ out)
{
  const int b = blockIdx.x;
  __shared__ float hv[HID];
  __shared__ float z1[128];
  __shared__ float z2[64];
  __shared__ float z3[32];
  const int tid = threadIdx.x;
  for (int i=tid;i<HID;i+=256) hv[i]=h1[(size_t)b*HID+i];
  __syncthreads();
  if (tid<128){
    float acc=bd1[tid]; const float* w=Wd1+(size_t)tid*512;
    for(int k=0;k<512;k++) acc+=hv[k]*w[k];
    z1[tid]=fmaxf(acc,0.f);
  }
  __syncthreads();
  if (tid<64){
    float acc=bd2[tid]; const float* w=Wd2+(size_t)tid*128;
    for(int k=0;k<128;k++) acc+=z1[k]*w[k];
    z2[tid]=fmaxf(acc,0.f);
  }
  __syncthreads();
  if (tid<32){
    float acc=bd3[tid]; const float* w=Wd3+(size_t)tid*64;
    for(int k=0;k<64;k++) acc+=z2[k]*w[k];
    z3[tid]=fmaxf(acc,0.f);
  }
  __syncthreads();
  if (tid==0){
    float acc=bd4[0];
    for(int k=0;k<32;k++) acc+=z3[k]*Wd4[k];
    out[b]=acc;
  }
}

extern "C" void kernel_launch(void* const* d_in, const int* in_sizes, int n_in,
                              void* d_out, int out_size, void* d_ws, size_t ws_size,
                              hipStream_t stream) {
  const float* x      = (const float*)d_in[0];
  const float* ln1_g  = (const float*)d_in[1];
  const float* ln1_b  = (const float*)d_in[2];
  const float* W_ih0  = (const float*)d_in[3];
  const float* b_ih0  = (const float*)d_in[4];
  const float* W_hh0  = (const float*)d_in[5];
  const float* b_hh0  = (const float*)d_in[6];
  const float* g_ih0  = (const float*)d_in[7];
  const float* be_ih0 = (const float*)d_in[8];
  const float* g_hh0  = (const float*)d_in[9];
  const float* be_hh0 = (const float*)d_in[10];
  const float* g_ho0  = (const float*)d_in[11];
  const float* be_ho0 = (const float*)d_in[12];
  const float* W_ih1  = (const float*)d_in[13];
  const float* b_ih1  = (const float*)d_in[14];
  const float* W_hh1  = (const float*)d_in[15];
  const float* b_hh1  = (const float*)d_in[16];
  const float* g_ih1  = (const float*)d_in[17];
  const float* be_ih1 = (const float*)d_in[18];
  const float* g_hh1  = (const float*)d_in[19];
  const float* be_hh1 = (const float*)d_in[20];
  const float* g_ho1  = (const float*)d_in[21];
  const float* be_ho1 = (const float*)d_in[22];
  const float* Wd1    = (const float*)d_in[23];
  const float* bd1    = (const float*)d_in[24];
  const float* Wd2    = (const float*)d_in[25];
  const float* bd2    = (const float*)d_in[26];
  const float* Wd3    = (const float*)d_in[27];
  const float* bd3    = (const float*)d_in[28];
  const float* Wd4    = (const float*)d_in[29];
  const float* bd4    = (const float*)d_in[30];
  float* out = (float*)d_out;

  // ---- workspace layout ----
  float* ws = (float*)d_ws;
  float* G  = ws;                                   // 7*512*2048 floats = 28 MB
  float* h0 = G  + NREG*(size_t)BATCH*GW;           // fp32 state block (zeroed)
  float* c0 = h0 + (size_t)BATCH*HID;
  float* h1 = c0 + (size_t)BATCH*HID;
  float* c1 = h1 + (size_t)BATCH*HID;
  half_t* h0h = (half_t*)(c1 + (size_t)BATCH*HID);  // fp16 state splits (zeroed)
  half_t* h0l = h0h + (size_t)BATCH*HID;
  half_t* h1h = h0l + (size_t)BATCH*HID;
  half_t* h1l = h1h + (size_t)BATCH*HID;
  float* mu = (float*)(h1l + (size_t)BATCH*HID);    // 512
  float* rs = mu + BATCH;                           // 512
  half_t* Wh = (half_t*)(rs + BATCH);               // WTOT halves
  half_t* Wl = Wh + (size_t)WTOT;                   // WTOT halves

  // zero h0,c0,h1,c1 (fp32) + h0h,h0l,h1h,h1l (fp16) in one contiguous memset
  hipMemsetAsync(h0, 0, 4*(size_t)BATCH*HID*4 + 4*(size_t)BATCH*HID*2, stream);

  ln1_stats<<<BATCH, 256, 0, stream>>>(x, mu, rs);
  wsplit<<<(WTOT+255)/256, 256, 0, stream>>>(W_ih0, W_hh0, W_ih1, W_hh1, Wh, Wl);

  dim3 mgrid(16, 8, NREG);
  for (int t = 0; t <= SEQ; ++t) {
    tick_mm16<<<mgrid, 256, 0, stream>>>(x, ln1_g, ln1_b, mu, rs,
        h0h, h0l, h1h, h1l, Wh, Wl, G, t);
    tick_update<<<dim3(1024), 256, 0, stream>>>(G,
        b_ih0, b_hh0, b_ih1, b_hh1,
        g_ih0, be_ih0, g_hh0, be_hh0, g_ho0, be_ho0,
        g_ih1, be_ih1, g_hh1, be_hh1, g_ho1, be_ho1,
        h0, c0, h1, c1, h0h, h0l, h1h, h1l, t);
  }
  head_kernel<<<BATCH, 256, 0, stream>>>(h1, Wd1, bd1, Wd2, bd2, Wd3, bd3, Wd4, bd4, out);
}

// Round 2
// 7091.399 us; speedup vs baseline: 1.6399x; 1.4518x over previous
//
#include <hip/hip_runtime.h>
#include <math.h>

#define BATCH 512
#define SEQ   200
#define DIN   64
#define HID   512
#define GW    2048   // 4*HID
#define EPS   1e-5f
#define NREG  7      // G regions: ih0 | hh0 x2 | ih1 x2 | hh1 x2

typedef _Float16 half_t;
typedef half_t half8 __attribute__((ext_vector_type(8)));
typedef float  f32x4  __attribute__((ext_vector_type(4)));
typedef float  f32x16 __attribute__((ext_vector_type(16)));

#define WN0 (2048*64)     // W_ih0 elems
#define WN1 (2048*512)    // W_hh0 / W_ih1 / W_hh1 elems
#define WTOT (WN0 + 3*WN1)

__device__ __forceinline__ float sigf(float x){ return 1.0f/(1.0f+expf(-x)); }

// Reduce 4 values across a 256-thread block. red must be float[16] shared.
__device__ __forceinline__ void block_reduce4(float&a,float&b,float&c,float&d,float* red){
  #pragma unroll
  for(int o=32;o;o>>=1){
    a+=__shfl_down(a,o); b+=__shfl_down(b,o);
    c+=__shfl_down(c,o); d+=__shfl_down(d,o);
  }
  const int lane = threadIdx.x & 63, wid = threadIdx.x>>6;
  if(lane==0){ red[wid*4+0]=a; red[wid*4+1]=b; red[wid*4+2]=c; red[wid*4+3]=d; }
  __syncthreads();
  a = red[0]+red[4]+red[8]+red[12];
  b = red[1]+red[5]+red[9]+red[13];
  c = red[2]+red[6]+red[10]+red[14];
  d = red[3]+red[7]+red[11]+red[15];
  __syncthreads();
}

// Per-batch-row stats for ln1 (joint LayerNorm over (S,D) = 12800 elems)
__global__ __launch_bounds__(256) void ln1_stats(const float* __restrict__ x,
                                                 float* __restrict__ mu,
                                                 float* __restrict__ rs){
  const int b = blockIdx.x;
  const float* xb = x + (size_t)b*SEQ*DIN;
  float s=0, ss=0, d=0, e=0;
  for (int i=threadIdx.x; i<SEQ*DIN; i+=256){ float v=xb[i]; s+=v; ss+=v*v; }
  __shared__ float red[16];
  block_reduce4(s,ss,d,e,red);
  if (threadIdx.x==0){
    float m = s*(1.0f/(SEQ*DIN));
    mu[b] = m;
    rs[b] = rsqrtf(ss*(1.0f/(SEQ*DIN)) - m*m + EPS);
  }
}

// Split the 4 weight matrices into fp16 hi/lo in FRAGMENT-MAJOR packed layout.
// Packed index within a region (Kd = 64 or 512, C = Kd/32):
//   idx = ((p*C + c)*4 + nf*2 + ks)*512 + l*8 + j
//   n = p*64 + nf*32 + (l&31);  k = c*32 + ks*16 + (l>>5)*8 + j
// so in the mm kernel a wave's B-fragment load is base + lane*16B: one
// fully-coalesced 1KB transaction, wave-uniform base (no per-lane addr mul).
__global__ __launch_bounds__(256) void wsplit(
    const float* __restrict__ W0, const float* __restrict__ W1,
    const float* __restrict__ W2, const float* __restrict__ W3,
    half_t* __restrict__ Wh, half_t* __restrict__ Wl)
{
  int i = blockIdx.x*256 + threadIdx.x;
  if (i >= WTOT) return;
  const float* src; int off, Kd;
  if (i < WN0){ src=W0; off=i; Kd=DIN; }
  else {
    int r = (i-WN0)/WN1; off = (i-WN0) - r*WN1; Kd=HID;
    src = (r==0)?W1:((r==1)?W2:W3);
  }
  const int C = Kd>>5;            // 2 or 16 (pow2)
  int j  = off & 7;
  int l  = (off>>3) & 63;
  int ks = (off>>9) & 1;
  int nf = (off>>10) & 1;
  int pc = off>>11;
  int c  = pc & (C-1);
  int p  = pc >> (Kd==DIN ? 1 : 4);
  int n  = p*64 + nf*32 + (l&31);
  int k  = c*32 + ks*16 + (l>>5)*8 + j;
  float v = src[(size_t)n*Kd + k];
  half_t h = (half_t)v;
  Wh[i] = h;
  Wl[i] = (half_t)(v - (float)h);
}

// One tick: gate pre-activation GEMMs via split-fp16 32x32x16 MFMA, layer-1 skewed.
// Split-K x2 on the three K=512 GEMMs. Packed weights; 2-deep register pipeline.
// grid.z = 7 regions:
//   z=0   : G_ih0 = ln1(x[:,t,:]) @ W_ih0^T   (K=64, A built in-register)
//   z=1,2 : G_hh0 = h0 @ W_hh0^T   k-halves 0/1
//   z=3,4 : G_ih1 = h0 @ W_ih1^T   k-halves 0/1
//   z=5,6 : G_hh1 = h1 @ W_hh1^T   k-halves 0/1
// Bias added in tick_update. grid = (16,8,7), block = 256 (4 waves, 2x2),
// wave tile 32m x 64n (one 32x32 acc pair).
__global__ __launch_bounds__(256) void tick_mm32(
    const float* __restrict__ x, const float* __restrict__ g1, const float* __restrict__ b1,
    const float* __restrict__ mu, const float* __restrict__ rsg,
    const half_t* __restrict__ h0h, const half_t* __restrict__ h0l,
    const half_t* __restrict__ h1h, const half_t* __restrict__ h1l,
    const half_t* __restrict__ Wh, const half_t* __restrict__ Wl,
    float* __restrict__ G, int t)
{
  const int z     = blockIdx.z;
  const int which = (z+1)>>1;            // 0,1,1,2,2,3,3
  const int khalf = z ? ((z-1)&1) : 0;
  const int tid  = threadIdx.x;
  const int lane = tid & 63;
  const int w    = tid >> 6;
  const int ln31 = lane & 31;
  const int lk8  = (lane >> 5) * 8;      // k sub-offset within a 16-chunk

  const int wm0 = blockIdx.y*64 + (w>>1)*32;   // wave m origin (32 rows)
  const int wn0 = blockIdx.x*128 + (w&1)*64;   // wave n origin (64 cols)
  const int p   = blockIdx.x*2 + (w&1);        // 64-col weight panel

  const half_t* Ah = h0h; const half_t* Al = h0l;
  const half_t* Bh = Wh + WN0; const half_t* Bl = Wl + WN0;
  int Kd = HID;
  if (which==0){ Bh=Wh; Bl=Wl; Kd=DIN; }
  else if (which==2){ Bh=Wh+WN0+WN1; Bl=Wl+WN0+WN1; }
  else if (which==3){ Ah=h1h; Al=h1l; Bh=Wh+WN0+2*WN1; Bl=Wl+WN0+2*WN1; }

  const int C    = Kd >> 5;
  const int kbeg = (which==0) ? 0 : khalf*(HID/2);
  const int kend = (which==0) ? DIN : (khalf*(HID/2) + HID/2);

  // wave-uniform packed-B bases (+ lane*8 elem = lane*16B)
  const half_t* Bph = Bh + (size_t)p*C*2048 + lane*8;
  const half_t* Bpl = Bl + (size_t)p*C*2048 + lane*8;

  const int tq = (t < SEQ) ? t : (SEQ-1);   // t==200 layer0 result unused

  // A addressing (row-major h state), hoisted
  const int arow = wm0 + ln31;
  const half_t* Ar  = Ah + (size_t)arow*HID + lk8;
  const half_t* Alr = Al + (size_t)arow*HID + lk8;
  float m_=0.f, r_=0.f;
  const float *xr=nullptr, *gr=nullptr, *br=nullptr;
  if (which==0){
    m_ = mu[arow]; r_ = rsg[arow];
    xr = x  + (size_t)arow*(SEQ*DIN) + (size_t)tq*DIN + lk8;
    gr = g1 + (size_t)tq*DIN + lk8;
    br = b1 + (size_t)tq*DIN + lk8;
  }

  f32x16 acc0 = {0.f,0.f,0.f,0.f,0.f,0.f,0.f,0.f,0.f,0.f,0.f,0.f,0.f,0.f,0.f,0.f};
  f32x16 acc1 = acc0;

  // --- load helpers (fully inlined; all indices compile-time) ---
  auto loadB = [&](half8&b0,half8&b1v,half8&b2,half8&b3,
                   half8&l0,half8&l1,half8&l2,half8&l3, int c_){
    const half_t* bb = Bph + (size_t)c_*2048;
    const half_t* ll = Bpl + (size_t)c_*2048;
    b0 = *(const half8*)(bb);       b1v = *(const half8*)(bb+512);
    b2 = *(const half8*)(bb+1024);  b3  = *(const half8*)(bb+1536);
    l0 = *(const half8*)(ll);       l1  = *(const half8*)(ll+512);
    l2 = *(const half8*)(ll+1024);  l3  = *(const half8*)(ll+1536);
  };
  auto loadA = [&](half8&a0,half8&a1,half8&q0,half8&q1, int k0_){
    if (which==0){
      #pragma unroll
      for (int ks=0; ks<2; ks++){
        const float* xp = xr + k0_ + ks*16;
        const float* gp = gr + k0_ + ks*16;
        const float* bp = br + k0_ + ks*16;
        half8 hv8, lv8;
        #pragma unroll
        for (int j=0;j<8;j++){
          float v = (xp[j]-m_)*r_*gp[j] + bp[j];
          half_t hv = (half_t)v;
          hv8[j] = hv; lv8[j] = (half_t)(v - (float)hv);
        }
        if (ks==0){ a0=hv8; q0=lv8; } else { a1=hv8; q1=lv8; }
      }
    } else {
      a0 = *(const half8*)(Ar  + k0_);
      a1 = *(const half8*)(Ar  + k0_ + 16);
      q0 = *(const half8*)(Alr + k0_);
      q1 = *(const half8*)(Alr + k0_ + 16);
    }
  };
  auto mmstep = [&](half8 a0,half8 a1,half8 q0,half8 q1,
                    half8 b0,half8 b1v,half8 b2,half8 b3,
                    half8 l0,half8 l1,half8 l2,half8 l3){
    // ks=0: frags b0 (nf0), b2 (nf1)
    acc0 = __builtin_amdgcn_mfma_f32_32x32x16_f16(a0, b0, acc0, 0,0,0);
    acc1 = __builtin_amdgcn_mfma_f32_32x32x16_f16(a0, b2, acc1, 0,0,0);
    acc0 = __builtin_amdgcn_mfma_f32_32x32x16_f16(q0, b0, acc0, 0,0,0);
    acc1 = __builtin_amdgcn_mfma_f32_32x32x16_f16(q0, b2, acc1, 0,0,0);
    acc0 = __builtin_amdgcn_mfma_f32_32x32x16_f16(a0, l0, acc0, 0,0,0);
    acc1 = __builtin_amdgcn_mfma_f32_32x32x16_f16(a0, l2, acc1, 0,0,0);
    // ks=1: frags b1 (nf0), b3 (nf1)
    acc0 = __builtin_amdgcn_mfma_f32_32x32x16_f16(a1, b1v, acc0, 0,0,0);
    acc1 = __builtin_amdgcn_mfma_f32_32x32x16_f16(a1, b3,  acc1, 0,0,0);
    acc0 = __builtin_amdgcn_mfma_f32_32x32x16_f16(q1, b1v, acc0, 0,0,0);
    acc1 = __builtin_amdgcn_mfma_f32_32x32x16_f16(q1, b3,  acc1, 0,0,0);
    acc0 = __builtin_amdgcn_mfma_f32_32x32x16_f16(a1, l1, acc0, 0,0,0);
    acc1 = __builtin_amdgcn_mfma_f32_32x32x16_f16(a1, l3, acc1, 0,0,0);
  };

  // --- 2-deep software pipeline over 32-k chunks (chunk count is even) ---
  half8 A0a,A0b,A0c,A0d, B0a,B0b,B0c,B0d, L0a,L0b,L0c,L0d;
  half8 A1a,A1b,A1c,A1d, B1a,B1b,B1c,B1d, L1a,L1b,L1c,L1d;

  loadA(A0a,A0b,A0c,A0d, kbeg);
  loadB(B0a,B0b,B0c,B0d, L0a,L0b,L0c,L0d, kbeg>>5);
  for (int k0 = kbeg; k0 < kend; k0 += 64){
    loadA(A1a,A1b,A1c,A1d, k0+32);
    loadB(B1a,B1b,B1c,B1d, L1a,L1b,L1c,L1d, (k0+32)>>5);
    mmstep(A0a,A0b,A0c,A0d, B0a,B0b,B0c,B0d, L0a,L0b,L0c,L0d);
    if (k0+64 < kend){
      loadA(A0a,A0b,A0c,A0d, k0+64);
      loadB(B0a,B0b,B0c,B0d, L0a,L0b,L0c,L0d, (k0+64)>>5);
    }
    mmstep(A1a,A1b,A1c,A1d, B1a,B1b,B1c,B1d, L1a,L1b,L1c,L1d);
  }

  // C/D layout 32x32: col = lane&31, row = (reg&3) + 8*(reg>>2) + 4*(lane>>5)
  float* Gout = G + (size_t)z*BATCH*GW;
  #pragma unroll
  for (int reg=0; reg<16; reg++){
    const int m = wm0 + (reg&3) + 8*(reg>>2) + 4*(lane>>5);
    __builtin_nontemporal_store(acc0[reg], &Gout[(size_t)m*GW + wn0 + ln31]);
    __builtin_nontemporal_store(acc1[reg], &Gout[(size_t)m*GW + wn0 + 32 + ln31]);
  }
}

// One block per (layer, batch-row): split-K sum + bias + gate LN + cell update + h LN.
__global__ __launch_bounds__(256) void tick_update(
    const float* __restrict__ G,
    const float* __restrict__ b_ih0, const float* __restrict__ b_hh0,
    const float* __restrict__ b_ih1, const float* __restrict__ b_hh1,
    const float* __restrict__ g_ih0, const float* __restrict__ be_ih0,
    const float* __restrict__ g_hh0, const float* __restrict__ be_hh0,
    const float* __restrict__ g_ho0, const float* __restrict__ be_ho0,
    const float* __restrict__ g_ih1, const float* __restrict__ be_ih1,
    const float* __restrict__ g_hh1, const float* __restrict__ be_hh1,
    const float* __restrict__ g_ho1, const float* __restrict__ be_ho1,
    float* __restrict__ h0, float* __restrict__ c0,
    float* __restrict__ h1, float* __restrict__ c1,
    half_t* __restrict__ h0h, half_t* __restrict__ h0l,
    half_t* __restrict__ h1h, half_t* __restrict__ h1l, int t)
{
  const int layer = blockIdx.x >> 9;
  const int b = blockIdx.x & 511;
  if (layer==0 && t>=SEQ) return;   // layer0 active ticks 0..199
  if (layer==1 && t==0)   return;   // layer1 active ticks 1..200 (processes step t-1)

  const float *GA0,*GA1,*GB0,*GB1,*bA,*bB,*gA,*beA,*gB,*beB,*gH,*bH;
  float *cs,*hs; half_t *hhx,*hlx;
  const size_t rb = (size_t)b*GW;
  if (layer==0){
    GA0 = G + rb;                        GA1 = nullptr;
    GB0 = G + (size_t)1*BATCH*GW + rb;   GB1 = G + (size_t)2*BATCH*GW + rb;
    bA=b_ih0; bB=b_hh0;
    gA=g_ih0; beA=be_ih0; gB=g_hh0; beB=be_hh0; gH=g_ho0; bH=be_ho0;
    cs = c0 + b*HID; hs = h0 + b*HID; hhx = h0h + b*HID; hlx = h0l + b*HID;
  } else {
    GA0 = G + (size_t)3*BATCH*GW + rb;   GA1 = G + (size_t)4*BATCH*GW + rb;
    GB0 = G + (size_t)5*BATCH*GW + rb;   GB1 = G + (size_t)6*BATCH*GW + rb;
    bA=b_ih1; bB=b_hh1;
    gA=g_ih1; beA=be_ih1; gB=g_hh1; beB=be_hh1; gH=g_ho1; bH=be_ho1;
    cs = c1 + b*HID; hs = h1 + b*HID; hhx = h1h + b*HID; hlx = h1l + b*HID;
  }

  const int tid = threadIdx.x;
  __shared__ float red[16];
  __shared__ __align__(16) float GS[2*GW];     // 16 KB: A-part then B-part
  __shared__ float su[HID];
  __shared__ float so[HID];

  // Pass 1 (float4): split-K sum + bias, stage into LDS, LN stats for both vectors
  float sa=0, ssa=0, sb=0, ssb=0;
  for (int i=tid*4; i<GW; i+=1024){
    f32x4 va = *(const f32x4*)(GA0+i);
    if (GA1) va += *(const f32x4*)(GA1+i);
    va += *(const f32x4*)(bA+i);
    *(f32x4*)(GS+i) = va;
    f32x4 vb = *(const f32x4*)(GB0+i);
    vb += *(const f32x4*)(GB1+i);
    vb += *(const f32x4*)(bB+i);
    *(f32x4*)(GS+GW+i) = vb;
    #pragma unroll
    for (int q=0;q<4;q++){
      sa += va[q]; ssa += va[q]*va[q];
      sb += vb[q]; ssb += vb[q]*vb[q];
    }
  }
  block_reduce4(sa,ssa,sb,ssb,red);   // internal __syncthreads covers GS visibility
  const float ma = sa*(1.0f/GW);
  const float ra = rsqrtf(ssa*(1.0f/GW) - ma*ma + EPS);
  const float mb = sb*(1.0f/GW);
  const float rb_ = rsqrtf(ssb*(1.0f/GW) - mb*mb + EPS);

  // Pass 2: gates (i,f,g,o split), cell update, tanh(c) stats
  float s_u=0, s_uu=0;
  for (int j=tid;j<HID;j+=256){
    float iv = ((GS[j      ]-ma)*ra*gA[j      ]+beA[j      ]) + ((GS[GW+j      ]-mb)*rb_*gB[j      ]+beB[j      ]);
    float fv = ((GS[j+  HID]-ma)*ra*gA[j+  HID]+beA[j+  HID]) + ((GS[GW+j+  HID]-mb)*rb_*gB[j+  HID]+beB[j+  HID]);
    float gv = ((GS[j+2*HID]-ma)*ra*gA[j+2*HID]+beA[j+2*HID]) + ((GS[GW+j+2*HID]-mb)*rb_*gB[j+2*HID]+beB[j+2*HID]);
    float ov = ((GS[j+3*HID]-ma)*ra*gA[j+3*HID]+beA[j+3*HID]) + ((GS[GW+j+3*HID]-mb)*rb_*gB[j+3*HID]+beB[j+3*HID]);
    float cn = sigf(fv)*cs[j] + sigf(iv)*tanhf(gv);
    cs[j] = cn;
    float u = tanhf(cn);
    su[j] = u; so[j] = sigf(ov);
    s_u += u; s_uu += u*u;
  }
  float d3=0,d4=0;
  block_reduce4(s_u,s_uu,d3,d4,red);
  const float mu_u = s_u*(1.0f/HID);
  const float ru   = rsqrtf(s_uu*(1.0f/HID) - mu_u*mu_u + EPS);

  // Pass 3: h = sigmoid(o) * LN(tanh(c)); emit fp32 + fp16 hi/lo split
  for (int j=tid;j<HID;j+=256){
    float v = so[j] * ((su[j]-mu_u)*ru*gH[j] + bH[j]);
    hs[j] = v;
    half_t hv = (half_t)v;
    hhx[j] = hv;
    hlx[j] = (half_t)(v - (float)hv);
  }
}

// Dense head: 512 -> 128 -> 64 -> 32 -> 1, one block per batch row
__global__ __launch_bounds__(256) void head_kernel(
    const float* __restrict__ h1,
    const float* __restrict__ Wd1, const float* __restrict__ bd1,
    const float* __restrict__ Wd2, const float* __restrict__ bd2,
    const float* __restrict__ Wd3, const float* __restrict__ bd3,
    const float* __restrict__ Wd4, const float* __restrict__ bd4,
    float* __restrict__ out)
{
  const int b = blockIdx.x;
  __shared__ float hv[HID];
  __shared__ float z1[128];
  __shared__ float z2[64];
  __shared__ float z3[32];
  const int tid = threadIdx.x;
  for (int i=tid;i<HID;i+=256) hv[i]=h1[(size_t)b*HID+i];
  __syncthreads();
  if (tid<128){
    float acc=bd1[tid]; const float* w=Wd1+(size_t)tid*512;
    for(int k=0;k<512;k++) acc+=hv[k]*w[k];
    z1[tid]=fmaxf(acc,0.f);
  }
  __syncthreads();
  if (tid<64){
    float acc=bd2[tid]; const float* w=Wd2+(size_t)tid*128;
    for(int k=0;k<128;k++) acc+=z1[k]*w[k];
    z2[tid]=fmaxf(acc,0.f);
  }
  __syncthreads();
  if (tid<32){
    float acc=bd3[tid]; const float* w=Wd3+(size_t)tid*64;
    for(int k=0;k<64;k++) acc+=z2[k]*w[k];
    z3[tid]=fmaxf(acc,0.f);
  }
  __syncthreads();
  if (tid==0){
    float acc=bd4[0];
    for(int k=0;k<32;k++) acc+=z3[k]*Wd4[k];
    out[b]=acc;
  }
}

extern "C" void kernel_launch(void* const* d_in, const int* in_sizes, int n_in,
                              void* d_out, int out_size, void* d_ws, size_t ws_size,
                              hipStream_t stream) {
  const float* x      = (const float*)d_in[0];
  const float* ln1_g  = (const float*)d_in[1];
  const float* ln1_b  = (const float*)d_in[2];
  const float* W_ih0  = (const float*)d_in[3];
  const float* b_ih0  = (const float*)d_in[4];
  const float* W_hh0  = (const float*)d_in[5];
  const float* b_hh0  = (const float*)d_in[6];
  const float* g_ih0  = (const float*)d_in[7];
  const float* be_ih0 = (const float*)d_in[8];
  const float* g_hh0  = (const float*)d_in[9];
  const float* be_hh0 = (const float*)d_in[10];
  const float* g_ho0  = (const float*)d_in[11];
  const float* be_ho0 = (const float*)d_in[12];
  const float* W_ih1  = (const float*)d_in[13];
  const float* b_ih1  = (const float*)d_in[14];
  const float* W_hh1  = (const float*)d_in[15];
  const float* b_hh1  = (const float*)d_in[16];
  const float* g_ih1  = (const float*)d_in[17];
  const float* be_ih1 = (const float*)d_in[18];
  const float* g_hh1  = (const float*)d_in[19];
  const float* be_hh1 = (const float*)d_in[20];
  const float* g_ho1  = (const float*)d_in[21];
  const float* be_ho1 = (const float*)d_in[22];
  const float* Wd1    = (const float*)d_in[23];
  const float* bd1    = (const float*)d_in[24];
  const float* Wd2    = (const float*)d_in[25];
  const float* bd2    = (const float*)d_in[26];
  const float* Wd3    = (const float*)d_in[27];
  const float* bd3    = (const float*)d_in[28];
  const float* Wd4    = (const float*)d_in[29];
  const float* bd4    = (const float*)d_in[30];
  float* out = (float*)d_out;

  // ---- workspace layout ----
  float* ws = (float*)d_ws;
  float* G  = ws;                                   // 7*512*2048 floats = 28 MB
  float* h0 = G  + NREG*(size_t)BATCH*GW;           // fp32 state block (zeroed)
  float* c0 = h0 + (size_t)BATCH*HID;
  float* c1 = c0 + (size_t)BATCH*HID;
  float* h1 = c1 + (size_t)BATCH*HID;
  half_t* h0h = (half_t*)(h1 + (size_t)BATCH*HID);  // fp16 state splits (zeroed)
  half_t* h0l = h0h + (size_t)BATCH*HID;
  half_t* h1h = h0l + (size_t)BATCH*HID;
  half_t* h1l = h1h + (size_t)BATCH*HID;
  float* mu = (float*)(h1l + (size_t)BATCH*HID);    // 512
  float* rs = mu + BATCH;                           // 512
  half_t* Wh = (half_t*)(rs + BATCH);               // WTOT halves (packed)
  half_t* Wl = Wh + (size_t)WTOT;                   // WTOT halves (packed)

  // zero h0,c0,c1,h1 (fp32) + h0h,h0l,h1h,h1l (fp16) in one contiguous memset
  hipMemsetAsync(h0, 0, 4*(size_t)BATCH*HID*4 + 4*(size_t)BATCH*HID*2, stream);

  ln1_stats<<<BATCH, 256, 0, stream>>>(x, mu, rs);
  wsplit<<<(WTOT+255)/256, 256, 0, stream>>>(W_ih0, W_hh0, W_ih1, W_hh1, Wh, Wl);

  dim3 mgrid(16, 8, NREG);
  for (int t = 0; t <= SEQ; ++t) {
    tick_mm32<<<mgrid, 256, 0, stream>>>(x, ln1_g, ln1_b, mu, rs,
        h0h, h0l, h1h, h1l, Wh, Wl, G, t);
    tick_update<<<dim3(1024), 256, 0, stream>>>(G,
        b_ih0, b_hh0, b_ih1, b_hh1,
        g_ih0, be_ih0, g_hh0, be_hh0, g_ho0, be_ho0,
        g_ih1, be_ih1, g_hh1, be_hh1, g_ho1, be_ho1,
        h0, c0, h1, c1, h0h, h0l, h1h, h1l, t);
  }
  head_kernel<<<BATCH, 256, 0, stream>>>(h1, Wd1, bd1, Wd2, bd2, Wd3, bd3, Wd4, bd4, out);
}